// Round 1
// baseline (488.294 us; speedup 1.0000x reference)
//
#include <hip/hip_runtime.h>
#include <math.h>

#define BATCH 8
#define NPTS  2048
#define KNBR  16
#define CIN   128
#define HIDD  128
#define COUT  128
// MSG_DIM = 2*CIN + 3 = 259

__global__ __launch_bounds__(128) void edgeconv_kernel(
    const float* __restrict__ h,
    const float* __restrict__ pos,
    const int*   __restrict__ idx,
    const float* __restrict__ W1,   // (259, 128) row-major
    const float* __restrict__ b1,   // (128)
    const float* __restrict__ W2,   // (128, 128) row-major
    const float* __restrict__ b2,   // (128)
    const float* __restrict__ gamma,
    const float* __restrict__ beta,
    float* __restrict__ out)        // (B, N, 128)
{
    const int node = blockIdx.x;          // 0 .. B*N-1
    const int b = node >> 11;             // / 2048
    const int n = node & 2047;            // % 2048
    const int t = threadIdx.x;            // 0..127 = output channel

    __shared__ float s_hi[CIN];
    __shared__ float s_dh[KNBR][CIN];     // h_j - h_i
    __shared__ float s_rel[KNBR][4];      // pos_j - pos_i (padded)
    __shared__ int   s_idx[KNBR];
    __shared__ float s_x1[KNBR][HIDD];    // hidden activations
    __shared__ float s_red[4];

    const float* hb = h   + (size_t)b * NPTS * CIN;
    const float* pb = pos + (size_t)b * NPTS * 3;

    // ---- stage h_i and neighbor indices ----
    s_hi[t] = hb[(size_t)n * CIN + t];
    if (t < KNBR) s_idx[t] = idx[(size_t)node * KNBR + t];
    __syncthreads();

    // ---- stage h_j - h_i (coalesced gather: 128 lanes walk one row) ----
    #pragma unroll 4
    for (int k = 0; k < KNBR; ++k) {
        int j = s_idx[k];
        s_dh[k][t] = hb[(size_t)j * CIN + t] - s_hi[t];
    }
    if (t < KNBR) {
        int j = s_idx[t];
        s_rel[t][0] = pb[3*j+0] - pb[3*n+0];
        s_rel[t][1] = pb[3*j+1] - pb[3*n+1];
        s_rel[t][2] = pb[3*j+2] - pb[3*n+2];
    }
    __syncthreads();

    // ---- phase 1: x1[k][t] = gelu( msg[k] . W1[:,t] + b1[t] ) ----
    // msg = [h_i | h_j - h_i | rel]; the h_i part is k-invariant -> hoist.
    float base = b1[t];
    {
        const float4* hi4 = reinterpret_cast<const float4*>(s_hi);
        for (int m4 = 0; m4 < CIN/4; ++m4) {
            float4 d = hi4[m4];
            float w0 = W1[(4*m4+0)*HIDD + t];
            float w1 = W1[(4*m4+1)*HIDD + t];
            float w2 = W1[(4*m4+2)*HIDD + t];
            float w3 = W1[(4*m4+3)*HIDD + t];
            base += d.x*w0 + d.y*w1 + d.z*w2 + d.w*w3;
        }
    }

    float acc[KNBR];
    #pragma unroll
    for (int k = 0; k < KNBR; ++k) acc[k] = base;

    {
        const float4* dh4 = reinterpret_cast<const float4*>(&s_dh[0][0]); // [KNBR][CIN/4]
        for (int m4 = 0; m4 < CIN/4; ++m4) {
            float w0 = W1[(CIN + 4*m4+0)*HIDD + t];
            float w1 = W1[(CIN + 4*m4+1)*HIDD + t];
            float w2 = W1[(CIN + 4*m4+2)*HIDD + t];
            float w3 = W1[(CIN + 4*m4+3)*HIDD + t];
            #pragma unroll
            for (int k = 0; k < KNBR; ++k) {
                float4 d = dh4[k*(CIN/4) + m4];
                acc[k] += d.x*w0 + d.y*w1 + d.z*w2 + d.w*w3;
            }
        }
        // rel part (3 dims)
        float wr0 = W1[(2*CIN+0)*HIDD + t];
        float wr1 = W1[(2*CIN+1)*HIDD + t];
        float wr2 = W1[(2*CIN+2)*HIDD + t];
        #pragma unroll
        for (int k = 0; k < KNBR; ++k) {
            acc[k] += s_rel[k][0]*wr0 + s_rel[k][1]*wr1 + s_rel[k][2]*wr2;
        }
    }

    // exact gelu, store hidden to LDS
    #pragma unroll
    for (int k = 0; k < KNBR; ++k) {
        float x = acc[k];
        s_x1[k][t] = 0.5f * x * (1.0f + erff(x * 0.70710678118654752f));
    }
    __syncthreads();

    // ---- phase 2: x2[k][t] = gelu( x1[k] . W2[:,t] + b2[t] ); max over k ----
    float acc2[KNBR];
    float bb = b2[t];
    #pragma unroll
    for (int k = 0; k < KNBR; ++k) acc2[k] = bb;

    {
        const float4* x14 = reinterpret_cast<const float4*>(&s_x1[0][0]); // [KNBR][HIDD/4]
        for (int m4 = 0; m4 < HIDD/4; ++m4) {
            float w0 = W2[(4*m4+0)*COUT + t];
            float w1 = W2[(4*m4+1)*COUT + t];
            float w2 = W2[(4*m4+2)*COUT + t];
            float w3 = W2[(4*m4+3)*COUT + t];
            #pragma unroll
            for (int k = 0; k < KNBR; ++k) {
                float4 d = x14[k*(HIDD/4) + m4];
                acc2[k] += d.x*w0 + d.y*w1 + d.z*w2 + d.w*w3;
            }
        }
    }

    float v = -3.402823466e+38f;
    #pragma unroll
    for (int k = 0; k < KNBR; ++k) {
        float x = acc2[k];
        float g = 0.5f * x * (1.0f + erff(x * 0.70710678118654752f));
        v = fmaxf(v, g);
    }

    // ---- layernorm over the 128 channels (2 waves) ----
    float s = v, s2 = v * v;
    #pragma unroll
    for (int off = 32; off > 0; off >>= 1) {
        s  += __shfl_down(s,  off, 64);
        s2 += __shfl_down(s2, off, 64);
    }
    const int wid  = t >> 6;
    const int lane = t & 63;
    if (lane == 0) { s_red[wid] = s; s_red[2 + wid] = s2; }
    __syncthreads();
    float S  = s_red[0] + s_red[1];
    float S2 = s_red[2] + s_red[3];
    float mu  = S * (1.0f / 128.0f);
    float var = S2 * (1.0f / 128.0f) - mu * mu;
    float inv = rsqrtf(var + 1e-5f);
    out[(size_t)node * COUT + t] = (v - mu) * inv * gamma[t] + beta[t];
}

extern "C" void kernel_launch(void* const* d_in, const int* in_sizes, int n_in,
                              void* d_out, int out_size, void* d_ws, size_t ws_size,
                              hipStream_t stream) {
    const float* h     = (const float*)d_in[0];
    const float* pos   = (const float*)d_in[1];
    const int*   idx   = (const int*)  d_in[2];
    const float* W1    = (const float*)d_in[3];
    const float* b1    = (const float*)d_in[4];
    const float* W2    = (const float*)d_in[5];
    const float* b2    = (const float*)d_in[6];
    const float* gamma = (const float*)d_in[7];
    const float* beta  = (const float*)d_in[8];
    float* out = (float*)d_out;

    dim3 grid(BATCH * NPTS);
    dim3 block(128);
    edgeconv_kernel<<<grid, block, 0, stream>>>(h, pos, idx, W1, b1, W2, b2,
                                                gamma, beta, out);
}

// Round 2
// 171.075 us; speedup vs baseline: 2.8543x; 2.8543x over previous
//
#include <hip/hip_runtime.h>
#include <math.h>

#define BATCH 8
#define NPTS  2048
#define KNBR  16
#define CIN   128
#define HIDD  128
#define COUT  128

#define WAVES 8            // 512 threads / block
#define NODES_PER_WAVE 8   // 256 blocks * 8 waves * 8 nodes = 16384 nodes

typedef __attribute__((ext_vector_type(8))) short bf16x8;
typedef __attribute__((ext_vector_type(4))) float f32x4;

// fp32 -> bf16 bits, round-nearest-even (finite inputs)
static __device__ __forceinline__ short f2bf(float f) {
    unsigned int x = __builtin_bit_cast(unsigned int, f);
    unsigned int r = (x + 0x7fffu + ((x >> 16) & 1u)) >> 16;
    return (short)r;
}

// tanh-approx gelu; |err| vs exact erf-gelu <= ~3e-3, well under threshold
static __device__ __forceinline__ float gelu(float x) {
    float u = 0.7978845608028654f * (x + 0.044715f * x * x * x);
    float e = __expf(2.0f * u);
    float t = 1.0f - 2.0f / (e + 1.0f);
    return 0.5f * x * (1.0f + t);
}

// ---------------- prep: swizzle W1/W2 into MFMA B-fragment order (bf16) ----
// B frag for 16x16x32: lane holds B[k = (lane>>4)*8 + j][n = nt*16 + (lane&15)]
// stored flat: frag[(nt*KSTEPS + ks)*64 + lane][j]  -> wave reads are
// perfectly lane-sequential 16B chunks (zero bank conflicts in LDS).
__global__ __launch_bounds__(256) void prep_weights(
    const float* __restrict__ W1, const float* __restrict__ W2,
    short* __restrict__ w1f, short* __restrict__ w2f)
{
    int tid = blockIdx.x * blockDim.x + threadIdx.x;
    if (tid < 32768) {                       // W1: 8 nt * 8 ks * 64 * 8
        int j = tid & 7, lane = (tid >> 3) & 63, ks = (tid >> 9) & 7, nt = tid >> 12;
        int k   = ks * 32 + (lane >> 4) * 8 + j;      // 0..255
        int col = nt * 16 + (lane & 15);
        w1f[tid] = f2bf(W1[k * HIDD + col]);
    } else if (tid < 49152) {                // W2: 8 nt * 4 ks * 64 * 8
        int t = tid - 32768;
        int j = t & 7, lane = (t >> 3) & 63, ks = (t >> 9) & 3, nt = t >> 11;
        int k   = ks * 32 + (lane >> 4) * 8 + j;      // 0..127
        int col = nt * 16 + (lane & 15);
        w2f[t] = f2bf(W2[k * COUT + col]);
    }
}

// ---------------- main kernel -------------------------------------------
// LDS: w1 frags 32768 shorts (64KB) | w2 frags 16384 shorts (32KB) |
//      hid tiles: 8 waves * 16 rows * 136 shorts (pad 128->136 keeps 16B
//      alignment and balanced banks) = 17408 shorts (34KB).  Total 130KB.
#define HID_STRIDE 136
#define LDS_SHORTS (32768 + 16384 + WAVES * 16 * HID_STRIDE)

__global__ __launch_bounds__(512, 2) void edgeconv_mfma(
    const float* __restrict__ h, const float* __restrict__ pos,
    const int* __restrict__ idx,
    const short* __restrict__ w1f, const short* __restrict__ w2f,
    const float* __restrict__ W1,           // for rel rows 256..258 (fp32)
    const float* __restrict__ b1, const float* __restrict__ b2,
    const float* __restrict__ gamma, const float* __restrict__ beta,
    float* __restrict__ out)
{
    extern __shared__ short lds[];
    short* s_w1  = lds;                 // 32768
    short* s_w2  = lds + 32768;         // 16384
    short* s_hid = lds + 49152;         // WAVES*16*HID_STRIDE

    const int tid  = threadIdx.x;
    const int wave = tid >> 6;
    const int lane = tid & 63;
    const int quad = lane >> 4;
    const int lm   = lane & 15;

    // ---- stage fragment-ordered weights into LDS (coalesced float4) ----
    {
        const float4* w1f4 = (const float4*)w1f;   // 4096 float4
        float4* d1 = (float4*)s_w1;
        for (int i = tid; i < 4096; i += 512) d1[i] = w1f4[i];
        const float4* w2f4 = (const float4*)w2f;   // 2048 float4
        float4* d2 = (float4*)s_w2;
        for (int i = tid; i < 2048; i += 512) d2[i] = w2f4[i];
    }
    __syncthreads();

    // ---- per-lane column constants (col = nt*16 + lm) ----
    float b1v[8], b2v[8], gv[8], bev[8], w1r0[8], w1r1[8], w1r2[8];
    #pragma unroll
    for (int nt = 0; nt < 8; ++nt) {
        int col = nt * 16 + lm;
        b1v[nt] = b1[col];  b2v[nt] = b2[col];
        gv[nt]  = gamma[col]; bev[nt] = beta[col];
        w1r0[nt] = W1[256 * HIDD + col];
        w1r1[nt] = W1[257 * HIDD + col];
        w1r2[nt] = W1[258 * HIDD + col];
    }

    const bf16x8* w1frag = (const bf16x8*)s_w1;
    const bf16x8* w2frag = (const bf16x8*)s_w2;
    short* hrow = s_hid + wave * 16 * HID_STRIDE;

    const int node0 = blockIdx.x * (WAVES * NODES_PER_WAVE) + wave * NODES_PER_WAVE;

    for (int ni = 0; ni < NODES_PER_WAVE; ++ni) {
        const int node = node0 + ni;
        const int b = node >> 11;
        const int n = node & 2047;
        const float* hb = h   + (size_t)b * NPTS * CIN;
        const float* pb = pos + (size_t)b * NPTS * 3;

        // neighbor index for row m = lm (duplicated across quads)
        const int jm = idx[node * KNBR + lm];

        // ---- build layer-1 A fragments (M=16 rows=k, K=256) ----
        // k in [0,128): h_i[k] (row-invariant);  k in [128,256): h_j-h_i
        const float4* hi4 = (const float4*)(hb + (size_t)n * CIN);
        const float4* hj4 = (const float4*)(hb + (size_t)jm * CIN);
        float4 hiA[8], hjA[8];
        #pragma unroll
        for (int ks = 0; ks < 4; ++ks) {
            hiA[2*ks]   = hi4[ks * 8 + quad * 2];
            hiA[2*ks+1] = hi4[ks * 8 + quad * 2 + 1];
            hjA[2*ks]   = hj4[ks * 8 + quad * 2];
            hjA[2*ks+1] = hj4[ks * 8 + quad * 2 + 1];
        }
        bf16x8 afrag[8];
        #pragma unroll
        for (int ks = 0; ks < 4; ++ks) {
            float4 a = hiA[2*ks], c = hiA[2*ks+1];
            afrag[ks] = bf16x8{f2bf(a.x), f2bf(a.y), f2bf(a.z), f2bf(a.w),
                               f2bf(c.x), f2bf(c.y), f2bf(c.z), f2bf(c.w)};
            float4 d0 = hjA[2*ks], d1 = hjA[2*ks+1];
            afrag[4+ks] = bf16x8{f2bf(d0.x-a.x), f2bf(d0.y-a.y), f2bf(d0.z-a.z), f2bf(d0.w-a.w),
                                 f2bf(d1.x-c.x), f2bf(d1.y-c.y), f2bf(d1.z-c.z), f2bf(d1.w-c.w)};
        }

        // ---- layer 1 MFMA: acc[nt] (C layout: col=nt*16+lm, row=quad*4+r) ----
        f32x4 acc[8];
        #pragma unroll
        for (int nt = 0; nt < 8; ++nt) acc[nt] = f32x4{0.f, 0.f, 0.f, 0.f};
        #pragma unroll
        for (int ks = 0; ks < 8; ++ks) {
            #pragma unroll
            for (int nt = 0; nt < 8; ++nt)
                acc[nt] = __builtin_amdgcn_mfma_f32_16x16x32_bf16(
                    afrag[ks], w1frag[(nt * 8 + ks) * 64 + lane], acc[nt], 0, 0, 0);
        }

        // ---- rel (3 cols of W1) correction, bias, gelu, write hidden ----
        float relr[4][3];
        const float px = pb[3*n], py = pb[3*n+1], pz = pb[3*n+2];
        #pragma unroll
        for (int r = 0; r < 4; ++r) {
            int m = quad * 4 + r;
            int jr = __shfl(jm, m, 64);
            relr[r][0] = pb[3*jr]   - px;
            relr[r][1] = pb[3*jr+1] - py;
            relr[r][2] = pb[3*jr+2] - pz;
        }
        #pragma unroll
        for (int nt = 0; nt < 8; ++nt) {
            #pragma unroll
            for (int r = 0; r < 4; ++r) {
                float x = acc[nt][r] + b1v[nt]
                        + relr[r][0] * w1r0[nt] + relr[r][1] * w1r1[nt]
                        + relr[r][2] * w1r2[nt];
                hrow[(quad * 4 + r) * HID_STRIDE + nt * 16 + lm] = f2bf(gelu(x));
            }
        }
        asm volatile("s_waitcnt lgkmcnt(0)" ::: "memory");

        // ---- layer 2: A = hidden (m=lm, k=quad*8+j within 32-chunk) ----
        bf16x8 a2[4];
        #pragma unroll
        for (int ks = 0; ks < 4; ++ks)
            a2[ks] = *(const bf16x8*)(hrow + lm * HID_STRIDE + ks * 32 + quad * 8);

        f32x4 acc2[8];
        #pragma unroll
        for (int nt = 0; nt < 8; ++nt) acc2[nt] = f32x4{0.f, 0.f, 0.f, 0.f};
        #pragma unroll
        for (int ks = 0; ks < 4; ++ks) {
            #pragma unroll
            for (int nt = 0; nt < 8; ++nt)
                acc2[nt] = __builtin_amdgcn_mfma_f32_16x16x32_bf16(
                    a2[ks], w2frag[(nt * 4 + ks) * 64 + lane], acc2[nt], 0, 0, 0);
        }

        // ---- gelu, max over rows (k), layernorm over 128 cols ----
        float vmax[8];
        #pragma unroll
        for (int nt = 0; nt < 8; ++nt) {
            float m0 = fmaxf(fmaxf(gelu(acc2[nt][0] + b2v[nt]),
                                   gelu(acc2[nt][1] + b2v[nt])),
                             fmaxf(gelu(acc2[nt][2] + b2v[nt]),
                                   gelu(acc2[nt][3] + b2v[nt])));
            m0 = fmaxf(m0, __shfl_xor(m0, 16, 64));
            m0 = fmaxf(m0, __shfl_xor(m0, 32, 64));
            vmax[nt] = m0;               // duplicated across quads
        }
        float s = 0.f, s2 = 0.f;
        #pragma unroll
        for (int nt = 0; nt < 8; ++nt) { s += vmax[nt]; s2 += vmax[nt] * vmax[nt]; }
        #pragma unroll
        for (int off = 1; off <= 8; off <<= 1) {
            s  += __shfl_xor(s,  off, 64);
            s2 += __shfl_xor(s2, off, 64);
        }
        const float mu  = s * (1.0f / 128.0f);
        const float var = s2 * (1.0f / 128.0f) - mu * mu;
        const float inv = rsqrtf(var + 1e-5f);

        float* orow = out + (size_t)node * COUT;
        #pragma unroll
        for (int t2 = 0; t2 < 2; ++t2) {
            int nt = quad * 2 + t2;      // quads split the 8 col-tiles
            orow[nt * 16 + lm] = (vmax[nt] - mu) * inv * gv[nt] + bev[nt];
        }
    }
}

extern "C" void kernel_launch(void* const* d_in, const int* in_sizes, int n_in,
                              void* d_out, int out_size, void* d_ws, size_t ws_size,
                              hipStream_t stream) {
    const float* h     = (const float*)d_in[0];
    const float* pos   = (const float*)d_in[1];
    const int*   idx   = (const int*)  d_in[2];
    const float* W1    = (const float*)d_in[3];
    const float* b1    = (const float*)d_in[4];
    const float* W2    = (const float*)d_in[5];
    const float* b2    = (const float*)d_in[6];
    const float* gamma = (const float*)d_in[7];
    const float* beta  = (const float*)d_in[8];
    float* out = (float*)d_out;

    short* w1f = (short*)d_ws;                 // 32768 bf16 = 64KB
    short* w2f = (short*)d_ws + 32768;         // 16384 bf16 = 32KB

    prep_weights<<<192, 256, 0, stream>>>(W1, W2, w1f, w2f);

    static bool attr_set = false;
    if (!attr_set) {
        hipFuncSetAttribute((const void*)edgeconv_mfma,
                            hipFuncAttributeMaxDynamicSharedMemorySize,
                            LDS_SHORTS * 2);
        attr_set = true;
    }

    dim3 grid(256);
    dim3 block(512);
    edgeconv_mfma<<<grid, block, LDS_SHORTS * 2, stream>>>(
        h, pos, idx, w1f, w2f, W1, b1, b2, gamma, beta, out);
}

// Round 3
// 128.052 us; speedup vs baseline: 3.8133x; 1.3360x over previous
//
#include <hip/hip_runtime.h>
#include <math.h>

#define BATCH 8
#define NPTS  2048
#define KNBR  16
#define CIN   128

typedef __attribute__((ext_vector_type(8))) short bf16x8;
typedef __attribute__((ext_vector_type(4))) float f32x4;

union U8 { bf16x8 v; unsigned u[4]; };

// gfx950 packed f32->bf16 convert (RNE). dst.lo16 = lo, dst.hi16 = hi.
static __device__ __forceinline__ unsigned pk2(float lo, float hi) {
    unsigned r;
    asm("v_cvt_pk_bf16_f32 %0, %1, %2" : "=v"(r) : "v"(lo), "v"(hi));
    return r;
}

// scalar RNE f32->bf16 (cold prep path only)
static __device__ __forceinline__ short f2bf(float f) {
    unsigned x = __builtin_bit_cast(unsigned, f);
    return (short)((x + 0x7fffu + ((x >> 16) & 1u)) >> 16);
}

// tanh-approx gelu in sigmoid form: x*sigma(2*0.79788*(x+0.044715x^3)). 8 inst.
static __device__ __forceinline__ float gelu(float x) {
    float x2 = x * x;
    float u  = x * fmaf(x2, 0.044715f, 1.0f);
    float e  = __expf(u * -1.5957691216057308f);
    return x * __builtin_amdgcn_rcpf(1.0f + e);
}

// ---------------------------------------------------------------------------
// prep: swizzle weights into MFMA B-fragment order (bf16) in d_ws.
// B frag (16x16x32): lane holds B[k=(lane>>4)*8+j][col=nt*16+(lane&15)].
//   w1a: W1 rows   0..127  -> frag f = nt*4+ks  (16384 shorts)
//   w1f: W1 rows 128..287  -> frag f = nt*5+ks  (20480 shorts; rows>=259 zero)
//   w2f: W2 rows   0..127  -> frag f = nt*4+ks  (16384 shorts)
__global__ __launch_bounds__(256) void prep_weights(
    const float* __restrict__ W1, const float* __restrict__ W2,
    short* __restrict__ wsb)
{
    int tid = blockIdx.x * 256 + threadIdx.x;          // grid 208 -> 53248
    if (tid >= 53248) return;
    if (tid < 16384) {                                  // w1a
        int j = tid & 7, lane = (tid >> 3) & 63, f = tid >> 9;
        int ks = f & 3, nt = f >> 2;
        int row = ks * 32 + (lane >> 4) * 8 + j, col = nt * 16 + (lane & 15);
        wsb[tid] = f2bf(W1[row * 128 + col]);
    } else if (tid < 36864) {                           // w1f
        int t = tid - 16384;
        int j = t & 7, lane = (t >> 3) & 63, f = t >> 9; // 0..39
        int ks = f % 5, nt = f / 5;
        int row = 128 + ks * 32 + (lane >> 4) * 8 + j, col = nt * 16 + (lane & 15);
        float v = (row < 259) ? W1[row * 128 + col] : 0.0f;
        wsb[tid] = f2bf(v);
    } else {                                            // w2f
        int t = tid - 36864;
        int j = t & 7, lane = (t >> 3) & 63, f = t >> 9;
        int ks = f & 3, nt = f >> 2;
        int row = ks * 32 + (lane >> 4) * 8 + j, col = nt * 16 + (lane & 15);
        wsb[36864 + t] = f2bf(W2[row * 128 + col]);
    }
}

// ---------------------------------------------------------------------------
// base pass: base[node][col] = h[node] . W1[0:128][col] + b1[col]  (fp32)
// One wave per 16 nodes; M=16 rows = nodes. 32 MFMA per wave.
__global__ __launch_bounds__(256) void base_pass(
    const float* __restrict__ h, const short* __restrict__ w1a,
    const float* __restrict__ b1, float* __restrict__ base)
{
    const int wave = threadIdx.x >> 6, lane = threadIdx.x & 63;
    const int quad = lane >> 4, lm = lane & 15;
    const int node0 = (blockIdx.x * 4 + wave) * 16;

    const float4* h4 = (const float4*)h;
    bf16x8 afrag[4];
    #pragma unroll
    for (int ks = 0; ks < 4; ++ks) {
        float4 p0 = h4[(size_t)(node0 + lm) * 32 + ks * 8 + quad * 2];
        float4 p1 = h4[(size_t)(node0 + lm) * 32 + ks * 8 + quad * 2 + 1];
        U8 t;
        t.u[0] = pk2(p0.x, p0.y); t.u[1] = pk2(p0.z, p0.w);
        t.u[2] = pk2(p1.x, p1.y); t.u[3] = pk2(p1.z, p1.w);
        afrag[ks] = t.v;
    }
    const bf16x8* bfr = (const bf16x8*)w1a;
    f32x4 acc[8];
    #pragma unroll
    for (int nt = 0; nt < 8; ++nt) {
        float bv = b1[nt * 16 + lm];
        acc[nt] = (f32x4){bv, bv, bv, bv};
    }
    #pragma unroll
    for (int ks = 0; ks < 4; ++ks)
        #pragma unroll
        for (int nt = 0; nt < 8; ++nt)
            acc[nt] = __builtin_amdgcn_mfma_f32_16x16x32_bf16(
                afrag[ks], bfr[(nt * 4 + ks) * 64 + lane], acc[nt], 0, 0, 0);
    #pragma unroll
    for (int nt = 0; nt < 8; ++nt)
        #pragma unroll
        for (int r = 0; r < 4; ++r)
            base[(size_t)(node0 + quad * 4 + r) * 128 + nt * 16 + lm] = acc[nt][r];
}

// ---------------------------------------------------------------------------
// main: per node, layer1 = base + (h_j-h_i)@W1[128:256] + rel@W1[256:259]
// (rel folded into MFMA as 5th K-step), gelu, layer2 MFMA, gelu-max via
// min/max unimodality trick, layernorm.
#define HSTR 136                    // hidden row stride (shorts), pad vs 128
#define MWAVES 16                   // 1024 threads
#define LDS_SHORTS (20480 + 16384 + MWAVES * 16 * HSTR)   // 143360 B total

__global__ __launch_bounds__(1024, 4) void edgeconv_main(
    const float* __restrict__ h, const float* __restrict__ pos,
    const int* __restrict__ idx,
    const short* __restrict__ w1f,      // w1f..w2f contiguous (73728 B)
    const float* __restrict__ base,
    const float* __restrict__ b2,
    const float* __restrict__ gamma, const float* __restrict__ beta,
    float* __restrict__ out)
{
    extern __shared__ short lds[];
    short* s_w1  = lds;                 // 20480 shorts
    short* s_w2  = lds + 20480;         // 16384 shorts
    short* s_hid = lds + 36864;

    const int tid = threadIdx.x, wave = tid >> 6, lane = tid & 63;
    const int quad = lane >> 4, lm = lane & 15;

    // stage both weight-fragment arrays (contiguous in ws) into LDS
    {
        const float4* src = (const float4*)w1f;     // 4608 float4
        float4* dst = (float4*)s_w1;
        for (int i = tid; i < 4608; i += 1024) dst[i] = src[i];
    }
    __syncthreads();

    float b2v[8];
    #pragma unroll
    for (int nt = 0; nt < 8; ++nt) b2v[nt] = b2[nt * 16 + lm];

    const bf16x8* w1frag = (const bf16x8*)s_w1;
    const bf16x8* w2frag = (const bf16x8*)s_w2;
    short* hrow = s_hid + wave * 16 * HSTR;

    // XCD swizzle: blocks on XCD x (blockIdx%8) take batch x's node range
    const int sb = (blockIdx.x & 7) * 32 + (blockIdx.x >> 3);
    const int node0 = sb * 64 + wave * 4;

    for (int ni = 0; ni < 4; ++ni) {
        const int node = node0 + ni;
        const int b = node >> 11, n = node & 2047;
        const float4* hb4 = (const float4*)(h + (size_t)b * NPTS * CIN);
        const float*  pb  = pos + (size_t)b * NPTS * 3;

        const int jm = idx[node * KNBR + lm];   // neighbor for row m=lm

        // ---- A frags: (h_j - h_i), k in [0,128) -> W1 rows 128..255 ----
        bf16x8 afrag[4];
        #pragma unroll
        for (int ks = 0; ks < 4; ++ks) {
            float4 a0 = hb4[n  * 32 + ks * 8 + quad * 2];
            float4 a1 = hb4[n  * 32 + ks * 8 + quad * 2 + 1];
            float4 j0 = hb4[jm * 32 + ks * 8 + quad * 2];
            float4 j1 = hb4[jm * 32 + ks * 8 + quad * 2 + 1];
            U8 t;
            t.u[0] = pk2(j0.x - a0.x, j0.y - a0.y);
            t.u[1] = pk2(j0.z - a0.z, j0.w - a0.w);
            t.u[2] = pk2(j1.x - a1.x, j1.y - a1.y);
            t.u[3] = pk2(j1.z - a1.z, j1.w - a1.w);
            afrag[ks] = t.v;
        }
        // ---- rel frag: 5th K-step; nonzero only quad 0, j=0..2 ----
        U8 rt; rt.u[0] = 0; rt.u[1] = 0; rt.u[2] = 0; rt.u[3] = 0;
        if (quad == 0) {
            float rx = pb[3 * jm]     - pb[3 * n];
            float ry = pb[3 * jm + 1] - pb[3 * n + 1];
            float rz = pb[3 * jm + 2] - pb[3 * n + 2];
            rt.u[0] = pk2(rx, ry);
            rt.u[1] = pk2(rz, 0.0f);
        }

        // ---- acc init from base (includes h_i part + b1) ----
        f32x4 acc[8];
        #pragma unroll
        for (int nt = 0; nt < 8; ++nt) {
            float bv = base[(size_t)node * 128 + nt * 16 + lm];
            acc[nt] = (f32x4){bv, bv, bv, bv};
        }
        #pragma unroll
        for (int ks = 0; ks < 4; ++ks)
            #pragma unroll
            for (int nt = 0; nt < 8; ++nt)
                acc[nt] = __builtin_amdgcn_mfma_f32_16x16x32_bf16(
                    afrag[ks], w1frag[(nt * 5 + ks) * 64 + lane], acc[nt], 0, 0, 0);
        #pragma unroll
        for (int nt = 0; nt < 8; ++nt)
            acc[nt] = __builtin_amdgcn_mfma_f32_16x16x32_bf16(
                rt.v, w1frag[(nt * 5 + 4) * 64 + lane], acc[nt], 0, 0, 0);

        // ---- gelu -> hidden tile (bf16) ----
        #pragma unroll
        for (int nt = 0; nt < 8; ++nt)
            #pragma unroll
            for (int r = 0; r < 4; ++r) {
                float g = gelu(acc[nt][r]);
                hrow[(quad * 4 + r) * HSTR + nt * 16 + lm] = (short)pk2(g, g);
            }
        asm volatile("s_waitcnt lgkmcnt(0)" ::: "memory");

        // ---- layer 2 ----
        bf16x8 a2[4];
        #pragma unroll
        for (int ks = 0; ks < 4; ++ks)
            a2[ks] = *(const bf16x8*)(hrow + lm * HSTR + ks * 32 + quad * 8);

        f32x4 acc2[8];
        #pragma unroll
        for (int nt = 0; nt < 8; ++nt) acc2[nt] = (f32x4){0.f, 0.f, 0.f, 0.f};
        #pragma unroll
        for (int ks = 0; ks < 4; ++ks)
            #pragma unroll
            for (int nt = 0; nt < 8; ++nt)
                acc2[nt] = __builtin_amdgcn_mfma_f32_16x16x32_bf16(
                    a2[ks], w2frag[(nt * 4 + ks) * 64 + lane], acc2[nt], 0, 0, 0);

        // ---- max_k gelu(x_k) = max(gelu(max x), gelu(min x)) (unimodal) ----
        float v[8];
        #pragma unroll
        for (int nt = 0; nt < 8; ++nt) {
            float mx = fmaxf(fmaxf(acc2[nt][0], acc2[nt][1]),
                             fmaxf(acc2[nt][2], acc2[nt][3]));
            float mn = fminf(fminf(acc2[nt][0], acc2[nt][1]),
                             fminf(acc2[nt][2], acc2[nt][3]));
            mx = fmaxf(mx, __shfl_xor(mx, 16, 64));
            mx = fmaxf(mx, __shfl_xor(mx, 32, 64));
            mn = fminf(mn, __shfl_xor(mn, 16, 64));
            mn = fminf(mn, __shfl_xor(mn, 32, 64));
            mx += b2v[nt]; mn += b2v[nt];
            v[nt] = fmaxf(gelu(mx), gelu(mn));
        }

        // ---- layernorm over 128 cols ----
        float s = 0.f, s2 = 0.f;
        #pragma unroll
        for (int nt = 0; nt < 8; ++nt) { s += v[nt]; s2 += v[nt] * v[nt]; }
        #pragma unroll
        for (int off = 1; off <= 8; off <<= 1) {
            s  += __shfl_xor(s,  off, 64);
            s2 += __shfl_xor(s2, off, 64);
        }
        const float mu  = s * (1.0f / 128.0f);
        const float var = s2 * (1.0f / 128.0f) - mu * mu;
        const float inv = rsqrtf(var + 1e-5f);

        float* orow = out + (size_t)node * 128;
        #pragma unroll
        for (int t2 = 0; t2 < 2; ++t2) {
            int nt = quad * 2 + t2, col = nt * 16 + lm;
            orow[col] = (v[nt] - mu) * inv * gamma[col] + beta[col];
        }
    }
}

extern "C" void kernel_launch(void* const* d_in, const int* in_sizes, int n_in,
                              void* d_out, int out_size, void* d_ws, size_t ws_size,
                              hipStream_t stream) {
    const float* h     = (const float*)d_in[0];
    const float* pos   = (const float*)d_in[1];
    const int*   idx   = (const int*)  d_in[2];
    const float* W1    = (const float*)d_in[3];
    const float* b1    = (const float*)d_in[4];
    const float* W2    = (const float*)d_in[5];
    const float* b2    = (const float*)d_in[6];
    const float* gamma = (const float*)d_in[7];
    const float* beta  = (const float*)d_in[8];
    float* out = (float*)d_out;

    // ws layout: [w1a 16384 sh][w1f 20480 sh][w2f 16384 sh][base 16384*128 f32]
    short* wsb  = (short*)d_ws;
    short* w1f  = wsb + 16384;
    float* base = (float*)((char*)d_ws + 106496);

    prep_weights<<<208, 256, 0, stream>>>(W1, W2, wsb);
    base_pass<<<256, 256, 0, stream>>>(h, wsb, b1, base);

    hipFuncSetAttribute((const void*)edgeconv_main,
                        hipFuncAttributeMaxDynamicSharedMemorySize,
                        LDS_SHORTS * 2);
    edgeconv_main<<<256, 1024, LDS_SHORTS * 2, stream>>>(
        h, pos, idx, w1f, base, b2, gamma, beta, out);
}

// Round 4
// 122.380 us; speedup vs baseline: 3.9900x; 1.0463x over previous
//
#include <hip/hip_runtime.h>
#include <math.h>

#define NPTS 2048
#define KNBR 16

typedef __attribute__((ext_vector_type(8))) short bf16x8;
typedef __attribute__((ext_vector_type(4))) float f32x4;
union U8 { bf16x8 v; unsigned u[4]; };

// gfx950 packed f32->bf16 (RNE)
static __device__ __forceinline__ unsigned pk2(float lo, float hi) {
    unsigned r;
    asm("v_cvt_pk_bf16_f32 %0, %1, %2" : "=v"(r) : "v"(lo), "v"(hi));
    return r;
}

// tanh-approx gelu (sigmoid form), ~8 VALU
static __device__ __forceinline__ float gelu(float x) {
    float x2 = x * x;
    float u  = x * fmaf(x2, 0.044715f, 1.0f);
    float e  = __expf(u * -1.5957691216057308f);
    return x * __builtin_amdgcn_rcpf(1.0f + e);
}

// LDS layout (shorts):
//   [0,20480)      w1f : W1 rows 128..287 (5 K-steps, rows>=259 zero), f=nt*5+ks
//   [20480,36864)  w2f : W2 rows 0..127 (4 K-steps),                   f=nt*4+ks
//   [36864,53248)  w1a : W1 rows 0..127 (4 K-steps), phase-B only      f=nt*4+ks
//   [36864,71680)  hidden tiles (16 waves * 16 * HSTR) -- OVERLAYS w1a after
//                  the phase-B barrier.
#define HSTR 136
#define LDS_SHORTS (36864 + 16 * 16 * HSTR)   // 71680 shorts = 143360 B

__global__ __launch_bounds__(1024, 4) void edgeconv_fused(
    const float* __restrict__ h, const float* __restrict__ pos,
    const int* __restrict__ idx,
    const float* __restrict__ W1, const float* __restrict__ W2,
    const float* __restrict__ b1, const float* __restrict__ b2,
    const float* __restrict__ gamma, const float* __restrict__ beta,
    float* __restrict__ out)
{
    extern __shared__ short lds[];
    const int tid = threadIdx.x, wave = tid >> 6, lane = tid & 63;
    const int quad = lane >> 4, lm = lane & 15;

    // ---- phase A: swizzle weights (global fp32 -> LDS bf16 B-fragments) ----
    // chunk c -> 8 shorts at lds[c*8]; fragment index fi = c>>6 is wave-uniform.
    for (int c = tid; c < 6656; c += 1024) {
        const int l = c & 63, fi = c >> 6;
        const int lrow = (l >> 4) * 8, lcol = l & 15;
        U8 t;
        if (fi < 40) {                        // w1f (W1 rows 128..287)
            int ks = fi % 5, nt = fi / 5;
            int row0 = 128 + ks * 32 + lrow, col = nt * 16 + lcol;
            #pragma unroll
            for (int p = 0; p < 4; ++p) {
                int r0 = row0 + 2 * p;
                float v0 = (r0     < 259) ? W1[r0 * 128 + col]       : 0.f;
                float v1 = (r0 + 1 < 259) ? W1[(r0 + 1) * 128 + col] : 0.f;
                t.u[p] = pk2(v0, v1);
            }
        } else if (fi < 72) {                 // w2f
            int f2 = fi - 40, ks = f2 & 3, nt = f2 >> 2;
            int row0 = ks * 32 + lrow, col = nt * 16 + lcol;
            #pragma unroll
            for (int p = 0; p < 4; ++p)
                t.u[p] = pk2(W2[(row0 + 2*p) * 128 + col],
                             W2[(row0 + 2*p + 1) * 128 + col]);
        } else {                              // w1a (W1 rows 0..127)
            int f2 = fi - 72, ks = f2 & 3, nt = f2 >> 2;
            int row0 = ks * 32 + lrow, col = nt * 16 + lcol;
            #pragma unroll
            for (int p = 0; p < 4; ++p)
                t.u[p] = pk2(W1[(row0 + 2*p) * 128 + col],
                             W1[(row0 + 2*p + 1) * 128 + col]);
        }
        ((bf16x8*)lds)[c] = t.v;
    }

    // per-lane constants
    float b1v[8], b2v[8];
    #pragma unroll
    for (int nt = 0; nt < 8; ++nt) {
        b1v[nt] = b1[nt * 16 + lm];
        b2v[nt] = b2[nt * 16 + lm];
    }
    const float gv0 = gamma[(quad * 2) * 16 + lm];
    const float gv1 = gamma[(quad * 2 + 1) * 16 + lm];
    const float be0 = beta[(quad * 2) * 16 + lm];
    const float be1 = beta[(quad * 2 + 1) * 16 + lm];

    __syncthreads();

    const bf16x8* w1frag  = (const bf16x8*)lds;          // f = nt*5+ks
    const bf16x8* w2frag  = (const bf16x8*)lds + 2560;   // f = nt*4+ks
    const bf16x8* w1afrag = (const bf16x8*)lds + 4608;   // f = nt*4+ks
    short* hrow = lds + 36864 + wave * 16 * HSTR;

    // XCD-aware node assignment; 256 blocks all co-resident (1 block/CU)
    const int sb = (blockIdx.x & 7) * 32 + (blockIdx.x >> 3);
    const int node0 = sb * 64 + wave * 4;

    // ---- phase B: base[node][col] = h_i . W1[0:128] + b1, in-register ----
    // A rows: node replicated x4 (row m -> node0 + (m&3)); C row quad*4+r
    // then holds node0+r, so basev[nt][r] = base(node0+r, nt*16+lm).
    f32x4 basev[8];
    #pragma unroll
    for (int nt = 0; nt < 8; ++nt)
        basev[nt] = (f32x4){b1v[nt], b1v[nt], b1v[nt], b1v[nt]};
    {
        const float4* hsrc = (const float4*)h + (size_t)(node0 + (lm & 3)) * 32;
        bf16x8 af[4];
        #pragma unroll
        for (int ks = 0; ks < 4; ++ks) {
            float4 p0 = hsrc[ks * 8 + quad * 2];
            float4 p1 = hsrc[ks * 8 + quad * 2 + 1];
            U8 t;
            t.u[0] = pk2(p0.x, p0.y); t.u[1] = pk2(p0.z, p0.w);
            t.u[2] = pk2(p1.x, p1.y); t.u[3] = pk2(p1.z, p1.w);
            af[ks] = t.v;
        }
        #pragma unroll
        for (int ks = 0; ks < 4; ++ks)
            #pragma unroll
            for (int nt = 0; nt < 8; ++nt)
                basev[nt] = __builtin_amdgcn_mfma_f32_16x16x32_bf16(
                    af[ks], w1afrag[(nt * 4 + ks) * 64 + lane], basev[nt], 0, 0, 0);
    }
    __syncthreads();   // hidden tiles overlay w1a beyond this point

    // ---- phase C: per-node edge MLP ----
    #pragma unroll
    for (int ni = 0; ni < 4; ++ni) {
        const int node = node0 + ni;
        const int b = node >> 11, n = node & 2047;
        const float4* hb4 = (const float4*)h + (size_t)b * NPTS * 32;
        const float*  pb  = pos + (size_t)b * NPTS * 3;

        const int jm = idx[node * KNBR + lm];   // neighbor for row m=lm

        // A frags: (h_j - h_i) -> W1 rows 128..255
        bf16x8 afrag[4];
        #pragma unroll
        for (int ks = 0; ks < 4; ++ks) {
            float4 a0 = hb4[n  * 32 + ks * 8 + quad * 2];
            float4 a1 = hb4[n  * 32 + ks * 8 + quad * 2 + 1];
            float4 j0 = hb4[jm * 32 + ks * 8 + quad * 2];
            float4 j1 = hb4[jm * 32 + ks * 8 + quad * 2 + 1];
            U8 t;
            t.u[0] = pk2(j0.x - a0.x, j0.y - a0.y);
            t.u[1] = pk2(j0.z - a0.z, j0.w - a0.w);
            t.u[2] = pk2(j1.x - a1.x, j1.y - a1.y);
            t.u[3] = pk2(j1.z - a1.z, j1.w - a1.w);
            afrag[ks] = t.v;
        }
        // rel as 5th K-step (nonzero only quad 0, j=0..2)
        U8 rt; rt.u[0] = 0; rt.u[1] = 0; rt.u[2] = 0; rt.u[3] = 0;
        if (quad == 0) {
            float rx = pb[3 * jm]     - pb[3 * n];
            float ry = pb[3 * jm + 1] - pb[3 * n + 1];
            float rz = pb[3 * jm + 2] - pb[3 * n + 2];
            rt.u[0] = pk2(rx, ry);
            rt.u[1] = pk2(rz, 0.0f);
        }

        // acc init from in-register base (h_i part + b1)
        f32x4 acc[8];
        #pragma unroll
        for (int nt = 0; nt < 8; ++nt) {
            float bv = basev[nt][ni];
            acc[nt] = (f32x4){bv, bv, bv, bv};
        }
        #pragma unroll
        for (int ks = 0; ks < 4; ++ks)
            #pragma unroll
            for (int nt = 0; nt < 8; ++nt)
                acc[nt] = __builtin_amdgcn_mfma_f32_16x16x32_bf16(
                    afrag[ks], w1frag[(nt * 5 + ks) * 64 + lane], acc[nt], 0, 0, 0);
        #pragma unroll
        for (int nt = 0; nt < 8; ++nt)
            acc[nt] = __builtin_amdgcn_mfma_f32_16x16x32_bf16(
                rt.v, w1frag[(nt * 5 + 4) * 64 + lane], acc[nt], 0, 0, 0);

        // gelu -> hidden tile (bf16)
        #pragma unroll
        for (int nt = 0; nt < 8; ++nt)
            #pragma unroll
            for (int r = 0; r < 4; ++r) {
                float g = gelu(acc[nt][r]);
                hrow[(quad * 4 + r) * HSTR + nt * 16 + lm] = (short)pk2(g, g);
            }
        asm volatile("s_waitcnt lgkmcnt(0)" ::: "memory");

        // layer 2
        bf16x8 a2[4];
        #pragma unroll
        for (int ks = 0; ks < 4; ++ks)
            a2[ks] = *(const bf16x8*)(hrow + lm * HSTR + ks * 32 + quad * 8);

        f32x4 acc2[8];
        #pragma unroll
        for (int nt = 0; nt < 8; ++nt) acc2[nt] = (f32x4){0.f, 0.f, 0.f, 0.f};
        #pragma unroll
        for (int ks = 0; ks < 4; ++ks)
            #pragma unroll
            for (int nt = 0; nt < 8; ++nt)
                acc2[nt] = __builtin_amdgcn_mfma_f32_16x16x32_bf16(
                    a2[ks], w2frag[(nt * 4 + ks) * 64 + lane], acc2[nt], 0, 0, 0);

        // max_k gelu(x_k) = max(gelu(max x), gelu(min x))
        float v[8];
        #pragma unroll
        for (int nt = 0; nt < 8; ++nt) {
            float mx = fmaxf(fmaxf(acc2[nt][0], acc2[nt][1]),
                             fmaxf(acc2[nt][2], acc2[nt][3]));
            float mn = fminf(fminf(acc2[nt][0], acc2[nt][1]),
                             fminf(acc2[nt][2], acc2[nt][3]));
            mx = fmaxf(mx, __shfl_xor(mx, 16, 64));
            mx = fmaxf(mx, __shfl_xor(mx, 32, 64));
            mn = fminf(mn, __shfl_xor(mn, 16, 64));
            mn = fminf(mn, __shfl_xor(mn, 32, 64));
            mx += b2v[nt]; mn += b2v[nt];
            v[nt] = fmaxf(gelu(mx), gelu(mn));
        }

        // layernorm over 128 cols
        float s = 0.f, s2 = 0.f;
        #pragma unroll
        for (int nt = 0; nt < 8; ++nt) { s += v[nt]; s2 += v[nt] * v[nt]; }
        #pragma unroll
        for (int off = 1; off <= 8; off <<= 1) {
            s  += __shfl_xor(s,  off, 64);
            s2 += __shfl_xor(s2, off, 64);
        }
        const float mu  = s * (1.0f / 128.0f);
        const float var = s2 * (1.0f / 128.0f) - mu * mu;
        const float inv = rsqrtf(var + 1e-5f);

        float* orow = out + (size_t)node * 128;
        orow[(quad * 2) * 16 + lm]     = (v[quad * 2]     - mu) * inv * gv0 + be0;
        orow[(quad * 2 + 1) * 16 + lm] = (v[quad * 2 + 1] - mu) * inv * gv1 + be1;
    }
}

extern "C" void kernel_launch(void* const* d_in, const int* in_sizes, int n_in,
                              void* d_out, int out_size, void* d_ws, size_t ws_size,
                              hipStream_t stream) {
    const float* h     = (const float*)d_in[0];
    const float* pos   = (const float*)d_in[1];
    const int*   idx   = (const int*)  d_in[2];
    const float* W1    = (const float*)d_in[3];
    const float* b1    = (const float*)d_in[4];
    const float* W2    = (const float*)d_in[5];
    const float* b2    = (const float*)d_in[6];
    const float* gamma = (const float*)d_in[7];
    const float* beta  = (const float*)d_in[8];
    float* out = (float*)d_out;

    hipFuncSetAttribute((const void*)edgeconv_fused,
                        hipFuncAttributeMaxDynamicSharedMemorySize,
                        LDS_SHORTS * 2);
    edgeconv_fused<<<256, 1024, LDS_SHORTS * 2, stream>>>(
        h, pos, idx, W1, W2, b1, b2, gamma, beta, out);
}